// Round 1
// baseline (155.446 us; speedup 1.0000x reference)
//
#include <hip/hip_runtime.h>
#include <hip/hip_bf16.h>
#include <math.h>

typedef __attribute__((ext_vector_type(8))) short bf16x8;
typedef __attribute__((ext_vector_type(4))) short bf16x4;
typedef __attribute__((ext_vector_type(4))) float f32x4;

// async global->LDS, 16B per lane. LDS dest = wave-uniform base + lane*16.
static __device__ __forceinline__ void gld16(const void* g, void* l) {
    __builtin_amdgcn_global_load_lds(
        (const __attribute__((address_space(1))) unsigned int*)g,
        (__attribute__((address_space(3))) unsigned int*)l, 16, 0, 0);
}

static __device__ __forceinline__ short f2bf_s(float f) {
    __hip_bfloat16 h = __float2bfloat16(f);
    short s;
    __builtin_memcpy(&s, &h, 2);
    return s;
}

// ---------------------------------------------------------------------------
// Kernel 1: merged PE+LayerNorm (blocks 0..4095) and W transpose+cast
// (blocks 4096..7167). Independent work, block-uniform branch.
// ---------------------------------------------------------------------------
__global__ __launch_bounds__(256) void peln_wt_kernel(
    const float* __restrict__ emb,
    const float* __restrict__ gamma,
    const float* __restrict__ beta,
    const float* __restrict__ Wq,
    const float* __restrict__ Wk,
    const float* __restrict__ Wv,
    __hip_bfloat16* __restrict__ x,
    __hip_bfloat16* __restrict__ Wt)
{
    const int tid = threadIdx.x;
    if (blockIdx.x < 4096) {
        const int row = blockIdx.x;
        const int t   = row & 1023;
        float4 e = ((const float4*)(emb + (size_t)row * 1024))[tid];
        float v[4] = {e.x, e.y, e.z, e.w};
        float s = 0.f, ss = 0.f;
        #pragma unroll
        for (int kk = 0; kk < 4; ++kk) {
            int c = tid * 4 + kk;
            float ang = (float)t * exp2f(-13.287712379549449f * (float)(c >> 1) * (1.0f / 512.0f));
            float pe  = (c & 1) ? __cosf(ang) : __sinf(ang);
            v[kk] += pe;
            s  += v[kk];
            ss += v[kk] * v[kk];
        }
        #pragma unroll
        for (int off = 1; off < 64; off <<= 1) {
            s  += __shfl_xor(s, off);
            ss += __shfl_xor(ss, off);
        }
        __shared__ float red_s[4], red_ss[4];
        int wave = tid >> 6, lane = tid & 63;
        if (lane == 0) { red_s[wave] = s; red_ss[wave] = ss; }
        __syncthreads();
        float S  = red_s[0] + red_s[1] + red_s[2] + red_s[3];
        float SS = red_ss[0] + red_ss[1] + red_ss[2] + red_ss[3];
        float mu   = S * (1.0f / 1024.0f);
        float var  = SS * (1.0f / 1024.0f) - mu * mu;
        float rstd = rsqrtf(var + 1e-5f);
        #pragma unroll
        for (int kk = 0; kk < 4; ++kk) {
            int c = tid * 4 + kk;
            float y = (v[kk] - mu) * rstd * gamma[c] + beta[c];
            x[(size_t)row * 1024 + c] = __float2bfloat16(y);
        }
    } else {
        __shared__ __hip_bfloat16 tile[32][33];
        int wid = blockIdx.x - 4096;         // 0..3071
        int zz  = wid >> 10;
        int rem = wid & 1023;
        int bx = rem & 31, by = rem >> 5;
        int tx = tid & 31, ty = tid >> 5;    // (32,8)
        const float* src = (zz == 0) ? Wq : (zz == 1) ? Wk : Wv;
        __hip_bfloat16* dst = Wt + (size_t)zz * 1024 * 1024;
        int x0 = bx * 32, y0 = by * 32;
        #pragma unroll
        for (int kk = 0; kk < 4; ++kk)
            tile[ty + 8 * kk][tx] =
                __float2bfloat16(src[(size_t)(y0 + ty + 8 * kk) * 1024 + x0 + tx]);
        __syncthreads();
        #pragma unroll
        for (int kk = 0; kk < 4; ++kk)
            dst[(size_t)(x0 + ty + 8 * kk) * 1024 + y0 + tx] = tile[tx][ty + 8 * kk];
    }
}

// ---------------------------------------------------------------------------
// Kernel 2: fused QKV GEMM — 256x256 tile, BK=64, 8 waves (512 thr),
// 8-phase schedule with counted vmcnt (T2+T3+T4+T5). Double-buffered LDS
// (2 x (A 32KB + B 32KB) = 128KB). Stage schedule (tile tau halves):
//   B-h0 @ (tau-2)p2, A-h0 @ (tau-2)p3, A-h1 @ (tau-1)p0, B-h1 @ (tau-1)p1
// Every stage targets a slot whose last reader is barrier-separated from the
// issue. Boundary wait: s_waitcnt vmcnt(4) (2 half-tiles in flight); vmcnt(0)
// only entering the final K-tile. Epilogue: two half-bounces through LDS.
// ---------------------------------------------------------------------------
__global__ __launch_bounds__(512, 2) void qkv_gemm(
    const __hip_bfloat16* __restrict__ X,    // [4096,1024] bf16
    const __hip_bfloat16* __restrict__ Wt,   // [3][1024][1024] bf16 N-major
    const float* __restrict__ bq,
    const float* __restrict__ bk,
    const float* __restrict__ bv,
    __hip_bfloat16* __restrict__ qkv,        // [2][4096][1024] bf16 (q,k)
    __hip_bfloat16* __restrict__ vt)         // [64][64][1024] bf16
{
    union SMem {
        struct { __hip_bfloat16 A[2][256 * 64]; __hip_bfloat16 B[2][256 * 64]; } s;
        __hip_bfloat16 C[128 * 264];         // epilogue bounce (half of C)
    };
    __shared__ __align__(16) SMem sm;

    const int id   = blockIdx.x;             // 0..191
    const int wgid = (id & 7) * 24 + (id >> 3);   // XCD-contiguous
    const int mb   = wgid / 12;              // 0..15
    const int nbt  = wgid % 12;              // 0..11
    const int m0   = mb * 256;
    const int t    = nbt >> 2;               // weight (q,k,v)
    const int nn0  = (nbt & 3) * 256;        // col offset within weight

    const int tid  = threadIdx.x;
    const int w8   = tid >> 6;               // wave 0..7
    const int lane = tid & 63;
    const int wm = w8 & 1, wn = w8 >> 1;     // 2M x 4N wave grid
    const int lm = lane & 15, quad = lane >> 4;
    const int srow = lane >> 3;              // 0..7
    const int skc  = ((lane & 7) ^ srow) * 8; // swizzled source chunk (elems)

    const __hip_bfloat16* Ag = X  + (size_t)m0 * 1024;
    const __hip_bfloat16* Bg = Wt + (size_t)t * 1024 * 1024 + (size_t)nn0 * 1024;

    // stage one 128-row half-tile: 8 waves x 2 gld16, 8 rows per gld16.
    auto stA = [&](int buf, int h, int kt) {
        __hip_bfloat16* l = &sm.s.A[buf][(h * 128 + w8 * 16) * 64];
        const __hip_bfloat16* g = Ag + (size_t)(h * 128 + w8 * 16 + srow) * 1024 + kt + skc;
        gld16(g, l);
        gld16(g + (size_t)8 * 1024, l + 8 * 64);
    };
    auto stB = [&](int buf, int h, int kt) {
        __hip_bfloat16* l = &sm.s.B[buf][(h * 128 + w8 * 16) * 64];
        const __hip_bfloat16* g = Bg + (size_t)(h * 128 + w8 * 16 + srow) * 1024 + kt + skc;
        gld16(g, l);
        gld16(g + (size_t)8 * 1024, l + 8 * 64);
    };

    f32x4 acc[8][4];
    #pragma unroll
    for (int i = 0; i < 8; ++i)
        #pragma unroll
        for (int j = 0; j < 4; ++j)
            acc[i][j] = (f32x4){0.f, 0.f, 0.f, 0.f};

    // prologue: tile0 fully + tile1 h0 halves (12 vmcnt items);
    // wait all but newest 4 -> tile0 landed.
    stB(0, 0, 0);  stA(0, 0, 0);  stA(0, 1, 0);  stB(0, 1, 0);
    stB(1, 0, 64); stA(1, 0, 64);
    asm volatile("s_waitcnt vmcnt(4)" ::: "memory");
    __builtin_amdgcn_s_barrier();

#define QPHASE(MQ, NQ, STAGE, TAIL) do {                                        \
    bf16x8 af[2][4], bb_[2][2];                                                 \
    _Pragma("unroll")                                                           \
    for (int ks = 0; ks < 2; ++ks) {                                            \
        _Pragma("unroll")                                                       \
        for (int mi = 0; mi < 4; ++mi)                                          \
            af[ks][mi] = *(const bf16x8*)(Ab                                    \
                + (size_t)((MQ) * 128 + wm * 64 + mi * 16 + lm) * 64            \
                + (((ks * 4 + quad) ^ (lm & 7)) * 8));                          \
        _Pragma("unroll")                                                       \
        for (int ni = 0; ni < 2; ++ni)                                          \
            bb_[ks][ni] = *(const bf16x8*)(Bb                                   \
                + (size_t)((NQ) * 128 + wn * 32 + ni * 16 + lm) * 64            \
                + (((ks * 4 + quad) ^ (lm & 7)) * 8));                          \
    }                                                                           \
    STAGE                                                                       \
    __builtin_amdgcn_s_barrier();                                               \
    asm volatile("s_waitcnt lgkmcnt(0)" ::: "memory");                          \
    __builtin_amdgcn_sched_barrier(0);                                          \
    __builtin_amdgcn_s_setprio(1);                                              \
    _Pragma("unroll")                                                           \
    for (int ks = 0; ks < 2; ++ks)                                              \
        _Pragma("unroll")                                                       \
        for (int mi = 0; mi < 4; ++mi)                                          \
            _Pragma("unroll")                                                   \
            for (int ni = 0; ni < 2; ++ni)                                      \
                acc[(MQ) * 4 + mi][(NQ) * 2 + ni] =                             \
                    __builtin_amdgcn_mfma_f32_16x16x32_bf16(af[ks][mi],         \
                        bb_[ks][ni], acc[(MQ) * 4 + mi][(NQ) * 2 + ni], 0, 0, 0);\
    __builtin_amdgcn_s_setprio(0);                                              \
    TAIL                                                                        \
    __builtin_amdgcn_s_barrier();                                               \
} while (0)

    for (int tt = 0; tt < 16; ++tt) {
        const __hip_bfloat16* Ab = sm.s.A[tt & 1];
        const __hip_bfloat16* Bb = sm.s.B[tt & 1];
        QPHASE(0, 0, { if (tt + 1 < 16) stA((tt + 1) & 1, 1, (tt + 1) * 64); }, {});
        QPHASE(1, 0, { if (tt + 1 < 16) stB((tt + 1) & 1, 1, (tt + 1) * 64); }, {});
        QPHASE(0, 1, { if (tt + 2 < 16) stB(tt & 1, 0, (tt + 2) * 64); }, {});
        QPHASE(1, 1, { if (tt + 2 < 16) stA(tt & 1, 0, (tt + 2) * 64); },
               { if (tt < 14)       asm volatile("s_waitcnt vmcnt(4)" ::: "memory");
                 else if (tt == 14) asm volatile("s_waitcnt vmcnt(0)" ::: "memory"); });
    }
#undef QPHASE

    __syncthreads();                         // full fence before LDS reuse

    if (t < 2) {
        const float* bias = (t == 0) ? bq : bk;
        __hip_bfloat16* outp = qkv + (size_t)t * 4096 * 1024;
        #pragma unroll
        for (int H = 0; H < 2; ++H) {
            if (H) __syncthreads();
            #pragma unroll
            for (int mi = 0; mi < 4; ++mi) {
                int lrow = wm * 64 + mi * 16 + quad * 4;
                #pragma unroll
                for (int n = 0; n < 4; ++n) {
                    int lcol = (n >> 1) * 128 + wn * 32 + (n & 1) * 16 + lm;
                    float bb = bias[nn0 + lcol];
                    #pragma unroll
                    for (int r = 0; r < 4; ++r)
                        sm.C[(size_t)(lrow + r) * 264 + lcol] =
                            __float2bfloat16(acc[H * 4 + mi][n][r] + bb);
                }
            }
            __syncthreads();
            #pragma unroll
            for (int c = 0; c < 8; ++c) {
                int g   = tid + 512 * c;         // 0..4095 chunks of 16B
                int row = g >> 5;                // 0..127
                int col = (g & 31) * 8;
                bf16x8 vch = *(const bf16x8*)&sm.C[(size_t)row * 264 + col];
                *(bf16x8*)(outp + (size_t)(m0 + H * 128 + row) * 1024 + nn0 + col) = vch;
            }
        }
    } else {
        const int b0 = m0 >> 10, tok0 = m0 & 1023;
        #pragma unroll
        for (int H = 0; H < 2; ++H) {            // H = column half
            if (H) __syncthreads();
            #pragma unroll
            for (int ni = 0; ni < 2; ++ni) {
                int lcol = wn * 32 + ni * 16 + lm;   // 0..127 within col-half
                float bb = bv[nn0 + H * 128 + lcol];
                #pragma unroll
                for (int m = 0; m < 8; ++m) {
                    int grow = (m >> 2) * 128 + wm * 64 + (m & 3) * 16 + quad * 4;
                    #pragma unroll
                    for (int r = 0; r < 4; ++r)
                        sm.C[(size_t)lcol * 264 + grow + r] =
                            __float2bfloat16(acc[m][H * 2 + ni][r] + bb);
                }
            }
            __syncthreads();
            #pragma unroll
            for (int c = 0; c < 8; ++c) {
                int g  = tid + 512 * c;          // 0..4095
                int d  = g >> 5;                 // 0..127 within col-half
                int tc = (g & 31) * 8;           // token chunk
                int dg = nn0 + H * 128 + d;      // global dh index
                int bh = b0 * 16 + (dg >> 6);
                bf16x8 vch = *(const bf16x8*)&sm.C[(size_t)d * 264 + tc];
                *(bf16x8*)(vt + ((size_t)bh * 64 + (dg & 63)) * 1024 + tok0 + tc) = vch;
            }
        }
    }
}

// ---------------------------------------------------------------------------
// Kernel 3: flash attention v8 (round-10 best) — LDS-staged K/V, 128-key
// tiles, 2 compute sub-rounds per stage. 128 q/block, 32 q/wave, max-free
// softmax, P^T via wave-private LDS (ds ops in-order per wave).
// ---------------------------------------------------------------------------
__global__ __launch_bounds__(256, 2) void attn_kernel(
    const __hip_bfloat16* __restrict__ q,    // [4096,1024]
    const __hip_bfloat16* __restrict__ k,    // [4096,1024]
    const __hip_bfloat16* __restrict__ vt,   // [64][64][1024]
    float* __restrict__ out)                 // [4096,1024] f32
{
    __shared__ __align__(16) __hip_bfloat16 Kbuf[128 * 64];   // 16 KB [key][d]
    __shared__ __align__(16) __hip_bfloat16 Vbuf[2][64 * 64]; // 16 KB [half][d][key]
    __shared__ short ldsPT[4][32][72];                        // 18 KB
    const int id   = blockIdx.x;             // 0..511
    const int bh   = (id & 7) * 8 + ((id >> 3) & 7);  // XCD-local K/V
    const int qblk = id >> 6;                // 0..7
    const int b = bh >> 4, h = bh & 15;
    const int wave = threadIdx.x >> 6, lane = threadIdx.x & 63;
    const int lm = lane & 15, quad = lane >> 4;
    const int qbase = qblk * 128 + wave * 32;
    const float CEXP = 0.18033688011112042f; // (1/8) * log2(e)

    bf16x8 bqf[2][2];
    #pragma unroll
    for (int i = 0; i < 2; ++i)
        #pragma unroll
        for (int ks = 0; ks < 2; ++ks)
            bqf[i][ks] = *(const bf16x8*)(q + (size_t)(b * 1024 + qbase + 16 * i + lm) * 1024
                                            + h * 64 + ks * 32 + quad * 8);

    const __hip_bfloat16* kg = k + (size_t)(b * 1024) * 1024 + h * 64;   // [key][d]
    const __hip_bfloat16* vg = vt + (size_t)bh * 64 * 1024;              // [d][key]
    const int srow = lane >> 3;                  // 0..7
    const int skc  = ((lane & 7) ^ srow) * 8;    // swizzled source chunk

    f32x4 OT[4][2];        // [nt = d-tile][i = q-tile]; rows = d, cols = q
    float li[2] = {0.f, 0.f};
    #pragma unroll
    for (int nt = 0; nt < 4; ++nt)
        #pragma unroll
        for (int i = 0; i < 2; ++i)
            OT[nt][i] = (f32x4){0.f, 0.f, 0.f, 0.f};

    for (int kt = 0; kt < 1024; kt += 128) {
        // ---- stage K [128 keys][64 d] and V [2][64 d][64 keys] ----
        #pragma unroll
        for (int n = 0; n < 4; ++n) {
            int r0 = wave * 32 + n * 8;
            gld16(kg + (size_t)(kt + r0 + srow) * 1024 + skc, Kbuf + r0 * 64);
        }
        {
            int half = wave >> 1;
            #pragma unroll
            for (int n = 0; n < 4; ++n) {
                int d0 = (wave & 1) * 32 + n * 8;
                gld16(vg + (size_t)(d0 + srow) * 1024 + kt + half * 64 + skc,
                      Vbuf[half] + d0 * 64);
            }
        }
        __syncthreads();

        #pragma unroll
        for (int sr = 0; sr < 2; ++sr) {
            bf16x8 ak[4][2], av[4][2];
            #pragma unroll
            for (int jt = 0; jt < 4; ++jt)
                #pragma unroll
                for (int ks = 0; ks < 2; ++ks)
                    ak[jt][ks] = *(const bf16x8*)(Kbuf + (size_t)(sr * 64 + 16 * jt + lm) * 64
                                                  + (((ks * 4 + quad) ^ (lm & 7)) * 8));
            #pragma unroll
            for (int nt = 0; nt < 4; ++nt)
                #pragma unroll
                for (int ks = 0; ks < 2; ++ks)
                    av[nt][ks] = *(const bf16x8*)(Vbuf[sr] + (size_t)(16 * nt + lm) * 64
                                                  + (((ks * 4 + quad) ^ (lm & 7)) * 8));
            if (sr == 1) __syncthreads();   // all tile reads done; next stage may write

            f32x4 ST[2][4];
            #pragma unroll
            for (int i = 0; i < 2; ++i)
                #pragma unroll
                for (int jt = 0; jt < 4; ++jt)
                    ST[i][jt] = (f32x4){0.f, 0.f, 0.f, 0.f};
            #pragma unroll
            for (int ks = 0; ks < 2; ++ks)
                #pragma unroll
                for (int i = 0; i < 2; ++i)
                    #pragma unroll
                    for (int jt = 0; jt < 4; ++jt)
                        ST[i][jt] = __builtin_amdgcn_mfma_f32_16x16x32_bf16(ak[jt][ks], bqf[i][ks], ST[i][jt], 0, 0, 0);

            #pragma unroll
            for (int i = 0; i < 2; ++i)
                #pragma unroll
                for (int jt = 0; jt < 4; ++jt) {
                    bf16x4 pk;
                    #pragma unroll
                    for (int r = 0; r < 4; ++r) {
                        float p = __builtin_amdgcn_exp2f(ST[i][jt][r] * CEXP);
                        li[i] += p;
                        pk[r] = f2bf_s(p);
                    }
                    *(bf16x4*)&ldsPT[wave][16 * i + lm][16 * jt + quad * 4] = pk;
                }

            bf16x8 bp[2][2];
            #pragma unroll
            for (int i = 0; i < 2; ++i)
                #pragma unroll
                for (int ks = 0; ks < 2; ++ks)
                    bp[i][ks] = *(const bf16x8*)&ldsPT[wave][16 * i + lm][ks * 32 + quad * 8];
            #pragma unroll
            for (int ks = 0; ks < 2; ++ks)
                #pragma unroll
                for (int nt = 0; nt < 4; ++nt)
                    #pragma unroll
                    for (int i = 0; i < 2; ++i)
                        OT[nt][i] = __builtin_amdgcn_mfma_f32_16x16x32_bf16(av[nt][ks], bp[i][ks], OT[nt][i], 0, 0, 0);
        }
    }

    #pragma unroll
    for (int i = 0; i < 2; ++i) {
        li[i] += __shfl_xor(li[i], 16);
        li[i] += __shfl_xor(li[i], 32);
    }

    #pragma unroll
    for (int i = 0; i < 2; ++i) {
        float inv = 1.0f / li[i];
        int qrow = qbase + 16 * i + lm;
        #pragma unroll
        for (int nt = 0; nt < 4; ++nt) {
            float4 o4 = {OT[nt][i][0] * inv, OT[nt][i][1] * inv,
                         OT[nt][i][2] * inv, OT[nt][i][3] * inv};
            *(float4*)(out + (size_t)(b * 1024 + qrow) * 1024 + h * 64 + 16 * nt + quad * 4) = o4;
        }
    }
}

// ---------------------------------------------------------------------------
extern "C" void kernel_launch(void* const* d_in, const int* in_sizes, int n_in,
                              void* d_out, int out_size, void* d_ws, size_t ws_size,
                              hipStream_t stream)
{
    const float* emb   = (const float*)d_in[0];
    const float* gamma = (const float*)d_in[1];
    const float* beta  = (const float*)d_in[2];
    const float* Wq    = (const float*)d_in[3];
    const float* bq    = (const float*)d_in[4];
    const float* Wk    = (const float*)d_in[5];
    const float* bk    = (const float*)d_in[6];
    const float* Wv    = (const float*)d_in[7];
    const float* bv    = (const float*)d_in[8];
    float* out = (float*)d_out;

    __hip_bfloat16* ws  = (__hip_bfloat16*)d_ws;
    __hip_bfloat16* x   = ws;                            //  4M elems bf16
    __hip_bfloat16* Wt  = x   + (size_t)4096 * 1024;     //  3M elems
    __hip_bfloat16* qkv = Wt  + (size_t)3 * 1024 * 1024; //  8M elems (q,k)
    __hip_bfloat16* vt  = qkv + (size_t)2 * 4096 * 1024; //  4M elems (38MB)

    peln_wt_kernel<<<4096 + 3072, 256, 0, stream>>>(emb, gamma, beta, Wq, Wk, Wv, x, Wt);
    qkv_gemm<<<192, 512, 0, stream>>>(x, Wt, bq, bk, bv, qkv, vt);
    attn_kernel<<<512, 256, 0, stream>>>(qkv, qkv + (size_t)4096 * 1024, vt, out);
}

// Round 2
// 149.931 us; speedup vs baseline: 1.0368x; 1.0368x over previous
//
#include <hip/hip_runtime.h>
#include <hip/hip_bf16.h>
#include <math.h>

typedef __attribute__((ext_vector_type(8))) short bf16x8;
typedef __attribute__((ext_vector_type(4))) short bf16x4;
typedef __attribute__((ext_vector_type(4))) float f32x4;

// async global->LDS, 16B per lane. LDS dest = wave-uniform base + lane*16.
static __device__ __forceinline__ void gld16(const void* g, void* l) {
    __builtin_amdgcn_global_load_lds(
        (const __attribute__((address_space(1))) unsigned int*)g,
        (__attribute__((address_space(3))) unsigned int*)l, 16, 0, 0);
}

static __device__ __forceinline__ short f2bf_s(float f) {
    __hip_bfloat16 h = __float2bfloat16(f);
    short s;
    __builtin_memcpy(&s, &h, 2);
    return s;
}

// ---------------------------------------------------------------------------
// Kernel 1: merged PE+LayerNorm (blocks 0..4095) and W transpose+cast
// (blocks 4096..7167). Independent work, block-uniform branch.
// ---------------------------------------------------------------------------
__global__ __launch_bounds__(256) void peln_wt_kernel(
    const float* __restrict__ emb,
    const float* __restrict__ gamma,
    const float* __restrict__ beta,
    const float* __restrict__ Wq,
    const float* __restrict__ Wk,
    const float* __restrict__ Wv,
    __hip_bfloat16* __restrict__ x,
    __hip_bfloat16* __restrict__ Wt)
{
    const int tid = threadIdx.x;
    if (blockIdx.x < 4096) {
        const int row = blockIdx.x;
        const int t   = row & 1023;
        float4 e = ((const float4*)(emb + (size_t)row * 1024))[tid];
        float v[4] = {e.x, e.y, e.z, e.w};
        float s = 0.f, ss = 0.f;
        #pragma unroll
        for (int kk = 0; kk < 4; ++kk) {
            int c = tid * 4 + kk;
            float ang = (float)t * exp2f(-13.287712379549449f * (float)(c >> 1) * (1.0f / 512.0f));
            float pe  = (c & 1) ? __cosf(ang) : __sinf(ang);
            v[kk] += pe;
            s  += v[kk];
            ss += v[kk] * v[kk];
        }
        #pragma unroll
        for (int off = 1; off < 64; off <<= 1) {
            s  += __shfl_xor(s, off);
            ss += __shfl_xor(ss, off);
        }
        __shared__ float red_s[4], red_ss[4];
        int wave = tid >> 6, lane = tid & 63;
        if (lane == 0) { red_s[wave] = s; red_ss[wave] = ss; }
        __syncthreads();
        float S  = red_s[0] + red_s[1] + red_s[2] + red_s[3];
        float SS = red_ss[0] + red_ss[1] + red_ss[2] + red_ss[3];
        float mu   = S * (1.0f / 1024.0f);
        float var  = SS * (1.0f / 1024.0f) - mu * mu;
        float rstd = rsqrtf(var + 1e-5f);
        #pragma unroll
        for (int kk = 0; kk < 4; ++kk) {
            int c = tid * 4 + kk;
            float y = (v[kk] - mu) * rstd * gamma[c] + beta[c];
            x[(size_t)row * 1024 + c] = __float2bfloat16(y);
        }
    } else {
        __shared__ __hip_bfloat16 tile[32][33];
        int wid = blockIdx.x - 4096;         // 0..3071
        int zz  = wid >> 10;
        int rem = wid & 1023;
        int bx = rem & 31, by = rem >> 5;
        int tx = tid & 31, ty = tid >> 5;    // (32,8)
        const float* src = (zz == 0) ? Wq : (zz == 1) ? Wk : Wv;
        __hip_bfloat16* dst = Wt + (size_t)zz * 1024 * 1024;
        int x0 = bx * 32, y0 = by * 32;
        #pragma unroll
        for (int kk = 0; kk < 4; ++kk)
            tile[ty + 8 * kk][tx] =
                __float2bfloat16(src[(size_t)(y0 + ty + 8 * kk) * 1024 + x0 + tx]);
        __syncthreads();
        #pragma unroll
        for (int kk = 0; kk < 4; ++kk)
            dst[(size_t)(x0 + ty + 8 * kk) * 1024 + y0 + tx] = tile[tx][ty + 8 * kk];
    }
}

// ---------------------------------------------------------------------------
// Kernel 2: fused QKV GEMM. m97 loop (BK=64, XOR-swizzled LDS) with ROTATED
// pipeline: stage(n+1) issued after barrier-2, before MFMA(n) — the MFMA
// block shadows the staging latency. Coalesced LDS-bounce epilogue;
// t==2 (V) bounce transposed straight into vt.  (round-0 proven version)
// ---------------------------------------------------------------------------
__global__ __launch_bounds__(256) void qkv_gemm(
    const __hip_bfloat16* __restrict__ X,    // [4096,1024] bf16
    const __hip_bfloat16* __restrict__ Wt,   // [3][1024][1024] bf16 N-major
    const float* __restrict__ bq,
    const float* __restrict__ bk,
    const float* __restrict__ bv,
    __hip_bfloat16* __restrict__ qkv,        // [2][4096][1024] bf16 (q,k)
    __hip_bfloat16* __restrict__ vt)         // [64][64][1024] bf16
{
    union SMem {
        struct { __hip_bfloat16 A[128 * 64]; __hip_bfloat16 B[128 * 64]; } s;
        __hip_bfloat16 C[128 * 132];         // epilogue bounce (pad 132)
    };
    __shared__ __align__(16) SMem sm;

    const int id   = blockIdx.x;             // 0..767
    const int xcd  = id & 7;
    const int rest = id >> 3;                // 0..95
    const int j    = rest % 3;
    const int mblk = rest / 3;               // 0..31
    const int m0   = mblk * 128;
    const int n0   = (xcd * 3 + j) * 128;    // 0..2944
    const int t    = n0 >> 10;
    const int nn0  = n0 & 1023;
    const __hip_bfloat16* W = Wt + (size_t)t * 1024 * 1024;

    const int tid  = threadIdx.x;
    const int wave = tid >> 6, lane = tid & 63;
    const int wm = wave & 1, wn = wave >> 1;
    const int lm = lane & 15, quad = lane >> 4;

    const int srow = lane >> 3;                        // 0..7
    const int skc  = ((lane & 7) ^ srow) * 8;          // element offset
    const int rbase = wave * 32;                       // rows this wave stages
    const __hip_bfloat16* gA = X + (size_t)(m0 + rbase + srow) * 1024 + skc;
    const __hip_bfloat16* gB = W + (size_t)(nn0 + rbase + srow) * 1024 + skc;
    __hip_bfloat16* lA = sm.s.A + rbase * 64;
    __hip_bfloat16* lB = sm.s.B + rbase * 64;

    f32x4 acc[4][4];
    #pragma unroll
    for (int i = 0; i < 4; ++i)
        #pragma unroll
        for (int jj = 0; jj < 4; ++jj)
            acc[i][jj] = (f32x4){0.f, 0.f, 0.f, 0.f};

    // prologue: stage tile 0
    #pragma unroll
    for (int n = 0; n < 4; ++n) {
        gld16(gA + (size_t)n * 8 * 1024, lA + n * 8 * 64);
        gld16(gB + (size_t)n * 8 * 1024, lB + n * 8 * 64);
    }

    for (int k0 = 0; k0 < 1024; k0 += 64) {
        __syncthreads();                     // drains stage(k0) (vmcnt in barrier)

        bf16x8 a[2][4], b[2][4];
        #pragma unroll
        for (int ks = 0; ks < 2; ++ks) {
            #pragma unroll
            for (int i = 0; i < 4; ++i) {
                int row = wm * 64 + i * 16 + lm;
                a[ks][i] = *(const bf16x8*)(sm.s.A + (size_t)row * 64
                                            + (((ks * 4 + quad) ^ (lm & 7)) * 8));
            }
            #pragma unroll
            for (int jj = 0; jj < 4; ++jj) {
                int row = wn * 64 + jj * 16 + lm;
                b[ks][jj] = *(const bf16x8*)(sm.s.B + (size_t)row * 64
                                             + (((ks * 4 + quad) ^ (lm & 7)) * 8));
            }
        }
        __syncthreads();                     // all LDS reads done

        if (k0 + 64 < 1024) {                // stage(k0+64) under MFMA shadow
            #pragma unroll
            for (int n = 0; n < 4; ++n) {
                gld16(gA + (size_t)n * 8 * 1024 + k0 + 64, lA + n * 8 * 64);
                gld16(gB + (size_t)n * 8 * 1024 + k0 + 64, lB + n * 8 * 64);
            }
        }

        #pragma unroll
        for (int ks = 0; ks < 2; ++ks)
            #pragma unroll
            for (int i = 0; i < 4; ++i)
                #pragma unroll
                for (int jj = 0; jj < 4; ++jj)
                    acc[i][jj] = __builtin_amdgcn_mfma_f32_16x16x32_bf16(a[ks][i], b[ks][jj], acc[i][jj], 0, 0, 0);
    }

    const float* bias = (t == 0) ? bq : (t == 1) ? bk : bv;
    if (t < 2) {
        #pragma unroll
        for (int jj = 0; jj < 4; ++jj) {
            int col = wn * 64 + jj * 16 + lm;
            float bb = bias[nn0 + col];
            #pragma unroll
            for (int i = 0; i < 4; ++i)
                #pragma unroll
                for (int r = 0; r < 4; ++r) {
                    int row = wm * 64 + i * 16 + quad * 4 + r;
                    sm.C[(size_t)row * 132 + col] = __float2bfloat16(acc[i][jj][r] + bb);
                }
        }
        __syncthreads();
        __hip_bfloat16* out = qkv + (size_t)t * 4096 * 1024;
        #pragma unroll
        for (int c = 0; c < 8; ++c) {
            int g = tid + 256 * c;               // 0..2047 chunks of 16B
            int row = g >> 4;
            int colc = (g & 15) * 8;
            bf16x8 vch = *(const bf16x8*)&sm.C[(size_t)row * 132 + colc];
            *(bf16x8*)(out + (size_t)(m0 + row) * 1024 + nn0 + colc) = vch;
        }
    } else {
        #pragma unroll
        for (int jj = 0; jj < 4; ++jj) {
            int col = wn * 64 + jj * 16 + lm;
            float bb = bias[nn0 + col];
            #pragma unroll
            for (int i = 0; i < 4; ++i)
                #pragma unroll
                for (int r = 0; r < 4; ++r) {
                    int row = wm * 64 + i * 16 + quad * 4 + r;
                    sm.C[(size_t)col * 132 + row] = __float2bfloat16(acc[i][jj][r] + bb);
                }
        }
        __syncthreads();
        const int bbase = (m0 >> 10) * 16 + (nn0 >> 6);
        const int mloc  = m0 & 1023;
        #pragma unroll
        for (int c = 0; c < 8; ++c) {
            int g = tid + 256 * c;               // 0..2047
            int col = g >> 4;                    // 0..127
            int rch = (g & 15) * 8;              // token chunk
            bf16x8 vch = *(const bf16x8*)&sm.C[(size_t)col * 132 + rch];
            int bh = bbase + (col >> 6);
            int d  = col & 63;
            *(bf16x8*)(vt + ((size_t)bh * 64 + d) * 1024 + mloc + rch) = vch;
        }
    }
}

// ---------------------------------------------------------------------------
// Kernel 3: flash attention v9 — double-buffered K/V staging. Stage(t+1) is
// issued right after the top-of-tile barrier, into the buffer whose readers
// all crossed that barrier; its latency hides under both compute sub-rounds.
// One barrier per tile (was 2). ldsPT: stride 72 -> 64 + 16B-unit XOR swizzle
// (same bank pattern as Kbuf reads) so total LDS = 80 KB -> 2 blocks/CU.
// ---------------------------------------------------------------------------
__global__ __launch_bounds__(256, 2) void attn_kernel(
    const __hip_bfloat16* __restrict__ q,    // [4096,1024]
    const __hip_bfloat16* __restrict__ k,    // [4096,1024]
    const __hip_bfloat16* __restrict__ vt,   // [64][64][1024]
    float* __restrict__ out)                 // [4096,1024] f32
{
    __shared__ __align__(16) __hip_bfloat16 Kbuf[2][128 * 64];   // 32 KB
    __shared__ __align__(16) __hip_bfloat16 Vbuf[2][2][64 * 64]; // 32 KB
    __shared__ short ldsPT[4][32 * 64];                          // 16 KB
    const int id   = blockIdx.x;             // 0..511
    const int bh   = (id & 7) * 8 + ((id >> 3) & 7);  // XCD-local K/V
    const int qblk = id >> 6;                // 0..7
    const int b = bh >> 4, h = bh & 15;
    const int wave = threadIdx.x >> 6, lane = threadIdx.x & 63;
    const int lm = lane & 15, quad = lane >> 4;
    const int qbase = qblk * 128 + wave * 32;
    const float CEXP = 0.18033688011112042f; // (1/8) * log2(e)

    bf16x8 bqf[2][2];
    #pragma unroll
    for (int i = 0; i < 2; ++i)
        #pragma unroll
        for (int ks = 0; ks < 2; ++ks)
            bqf[i][ks] = *(const bf16x8*)(q + (size_t)(b * 1024 + qbase + 16 * i + lm) * 1024
                                            + h * 64 + ks * 32 + quad * 8);

    const __hip_bfloat16* kg = k + (size_t)(b * 1024) * 1024 + h * 64;   // [key][d]
    const __hip_bfloat16* vg = vt + (size_t)bh * 64 * 1024;              // [d][key]
    const int srow = lane >> 3;                  // 0..7
    const int skc  = ((lane & 7) ^ srow) * 8;    // swizzled source chunk

    f32x4 OT[4][2];        // [nt = d-tile][i = q-tile]; rows = d, cols = q
    float li[2] = {0.f, 0.f};
    #pragma unroll
    for (int nt = 0; nt < 4; ++nt)
        #pragma unroll
        for (int i = 0; i < 2; ++i)
            OT[nt][i] = (f32x4){0.f, 0.f, 0.f, 0.f};

    // stage K [128 keys][64 d] and V [2][64 d][64 keys] for tile `kt` into buf
    auto stageKV = [&](int buf, int kt) {
        #pragma unroll
        for (int n = 0; n < 4; ++n) {
            int r0 = wave * 32 + n * 8;
            gld16(kg + (size_t)(kt + r0 + srow) * 1024 + skc, Kbuf[buf] + r0 * 64);
        }
        int half = wave >> 1;
        #pragma unroll
        for (int n = 0; n < 4; ++n) {
            int d0 = (wave & 1) * 32 + n * 8;
            gld16(vg + (size_t)(d0 + srow) * 1024 + kt + half * 64 + skc,
                  Vbuf[buf][half] + d0 * 64);
        }
    };

    stageKV(0, 0);                           // prologue

    for (int tt = 0; tt < 8; ++tt) {
        __syncthreads();                     // stage(tt) landed; buf^1 readers done
        if (tt + 1 < 8) stageKV((tt + 1) & 1, (tt + 1) * 128);

        const __hip_bfloat16* Kb = Kbuf[tt & 1];

        #pragma unroll
        for (int sr = 0; sr < 2; ++sr) {
            const __hip_bfloat16* Vb = Vbuf[tt & 1][sr];
            bf16x8 ak[4][2], av[4][2];
            #pragma unroll
            for (int jt = 0; jt < 4; ++jt)
                #pragma unroll
                for (int ks = 0; ks < 2; ++ks)
                    ak[jt][ks] = *(const bf16x8*)(Kb + (size_t)(sr * 64 + 16 * jt + lm) * 64
                                                  + (((ks * 4 + quad) ^ (lm & 7)) * 8));
            #pragma unroll
            for (int nt = 0; nt < 4; ++nt)
                #pragma unroll
                for (int ks = 0; ks < 2; ++ks)
                    av[nt][ks] = *(const bf16x8*)(Vb + (size_t)(16 * nt + lm) * 64
                                                  + (((ks * 4 + quad) ^ (lm & 7)) * 8));

            f32x4 ST[2][4];
            #pragma unroll
            for (int i = 0; i < 2; ++i)
                #pragma unroll
                for (int jt = 0; jt < 4; ++jt)
                    ST[i][jt] = (f32x4){0.f, 0.f, 0.f, 0.f};
            #pragma unroll
            for (int ks = 0; ks < 2; ++ks)
                #pragma unroll
                for (int i = 0; i < 2; ++i)
                    #pragma unroll
                    for (int jt = 0; jt < 4; ++jt)
                        ST[i][jt] = __builtin_amdgcn_mfma_f32_16x16x32_bf16(ak[jt][ks], bqf[i][ks], ST[i][jt], 0, 0, 0);

            // P^T into wave-private LDS, 16B-unit XOR swizzle (row = 16i+lm)
            #pragma unroll
            for (int i = 0; i < 2; ++i)
                #pragma unroll
                for (int jt = 0; jt < 4; ++jt) {
                    bf16x4 pk;
                    #pragma unroll
                    for (int r = 0; r < 4; ++r) {
                        float p = __builtin_amdgcn_exp2f(ST[i][jt][r] * CEXP);
                        li[i] += p;
                        pk[r] = f2bf_s(p);
                    }
                    int u = jt * 2 + (quad >> 1);
                    *(bf16x4*)&ldsPT[wave][(16 * i + lm) * 64
                        + ((u ^ (lm & 7)) << 3) + (quad & 1) * 4] = pk;
                }

            bf16x8 bp[2][2];
            #pragma unroll
            for (int i = 0; i < 2; ++i)
                #pragma unroll
                for (int ks = 0; ks < 2; ++ks)
                    bp[i][ks] = *(const bf16x8*)&ldsPT[wave][(16 * i + lm) * 64
                        + (((ks * 4 + quad) ^ (lm & 7)) << 3)];
            #pragma unroll
            for (int ks = 0; ks < 2; ++ks)
                #pragma unroll
                for (int nt = 0; nt < 4; ++nt)
                    #pragma unroll
                    for (int i = 0; i < 2; ++i)
                        OT[nt][i] = __builtin_amdgcn_mfma_f32_16x16x32_bf16(av[nt][ks], bp[i][ks], OT[nt][i], 0, 0, 0);
        }
    }

    #pragma unroll
    for (int i = 0; i < 2; ++i) {
        li[i] += __shfl_xor(li[i], 16);
        li[i] += __shfl_xor(li[i], 32);
    }

    #pragma unroll
    for (int i = 0; i < 2; ++i) {
        float inv = 1.0f / li[i];
        int qrow = qbase + 16 * i + lm;
        #pragma unroll
        for (int nt = 0; nt < 4; ++nt) {
            float4 o4 = {OT[nt][i][0] * inv, OT[nt][i][1] * inv,
                         OT[nt][i][2] * inv, OT[nt][i][3] * inv};
            *(float4*)(out + (size_t)(b * 1024 + qrow) * 1024 + h * 64 + 16 * nt + quad * 4) = o4;
        }
    }
}

// ---------------------------------------------------------------------------
extern "C" void kernel_launch(void* const* d_in, const int* in_sizes, int n_in,
                              void* d_out, int out_size, void* d_ws, size_t ws_size,
                              hipStream_t stream)
{
    const float* emb   = (const float*)d_in[0];
    const float* gamma = (const float*)d_in[1];
    const float* beta  = (const float*)d_in[2];
    const float* Wq    = (const float*)d_in[3];
    const float* bq    = (const float*)d_in[4];
    const float* Wk    = (const float*)d_in[5];
    const float* bk    = (const float*)d_in[6];
    const float* Wv    = (const float*)d_in[7];
    const float* bv    = (const float*)d_in[8];
    float* out = (float*)d_out;

    __hip_bfloat16* ws  = (__hip_bfloat16*)d_ws;
    __hip_bfloat16* x   = ws;                            //  4M elems bf16
    __hip_bfloat16* Wt  = x   + (size_t)4096 * 1024;     //  3M elems
    __hip_bfloat16* qkv = Wt  + (size_t)3 * 1024 * 1024; //  8M elems (q,k)
    __hip_bfloat16* vt  = qkv + (size_t)2 * 4096 * 1024; //  4M elems (38MB)

    peln_wt_kernel<<<4096 + 3072, 256, 0, stream>>>(emb, gamma, beta, Wq, Wk, Wv, x, Wt);
    qkv_gemm<<<768, 256, 0, stream>>>(x, Wt, bq, bk, bv, qkv, vt);
    attn_kernel<<<512, 256, 0, stream>>>(qkv, qkv + (size_t)4096 * 1024, vt, out);
}

// Round 3
// 149.710 us; speedup vs baseline: 1.0383x; 1.0015x over previous
//
#include <hip/hip_runtime.h>
#include <hip/hip_bf16.h>
#include <math.h>

typedef __attribute__((ext_vector_type(8))) short bf16x8;
typedef __attribute__((ext_vector_type(4))) float f32x4;
typedef __attribute__((ext_vector_type(16))) float f32x16;

// async global->LDS, 16B per lane. LDS dest = wave-uniform base + lane*16.
static __device__ __forceinline__ void gld16(const void* g, void* l) {
    __builtin_amdgcn_global_load_lds(
        (const __attribute__((address_space(1))) unsigned int*)g,
        (__attribute__((address_space(3))) unsigned int*)l, 16, 0, 0);
}

// v_cvt_pk_bf16_f32: packs 2 f32 -> 2 bf16 in one u32 (lo = first arg).
static __device__ __forceinline__ unsigned cvtpk(float lo, float hi) {
    unsigned r;
    asm("v_cvt_pk_bf16_f32 %0, %1, %2" : "=v"(r) : "v"(lo), "v"(hi));
    return r;
}

// ---------------------------------------------------------------------------
// Kernel 1: merged PE+LayerNorm (blocks 0..4095) and W transpose+cast
// (blocks 4096..7167). Independent work, block-uniform branch.
// ---------------------------------------------------------------------------
__global__ __launch_bounds__(256) void peln_wt_kernel(
    const float* __restrict__ emb,
    const float* __restrict__ gamma,
    const float* __restrict__ beta,
    const float* __restrict__ Wq,
    const float* __restrict__ Wk,
    const float* __restrict__ Wv,
    __hip_bfloat16* __restrict__ x,
    __hip_bfloat16* __restrict__ Wt)
{
    const int tid = threadIdx.x;
    if (blockIdx.x < 4096) {
        const int row = blockIdx.x;
        const int t   = row & 1023;
        float4 e = ((const float4*)(emb + (size_t)row * 1024))[tid];
        float v[4] = {e.x, e.y, e.z, e.w};
        float s = 0.f, ss = 0.f;
        #pragma unroll
        for (int kk = 0; kk < 4; ++kk) {
            int c = tid * 4 + kk;
            float ang = (float)t * exp2f(-13.287712379549449f * (float)(c >> 1) * (1.0f / 512.0f));
            float pe  = (c & 1) ? __cosf(ang) : __sinf(ang);
            v[kk] += pe;
            s  += v[kk];
            ss += v[kk] * v[kk];
        }
        #pragma unroll
        for (int off = 1; off < 64; off <<= 1) {
            s  += __shfl_xor(s, off);
            ss += __shfl_xor(ss, off);
        }
        __shared__ float red_s[4], red_ss[4];
        int wave = tid >> 6, lane = tid & 63;
        if (lane == 0) { red_s[wave] = s; red_ss[wave] = ss; }
        __syncthreads();
        float S  = red_s[0] + red_s[1] + red_s[2] + red_s[3];
        float SS = red_ss[0] + red_ss[1] + red_ss[2] + red_ss[3];
        float mu   = S * (1.0f / 1024.0f);
        float var  = SS * (1.0f / 1024.0f) - mu * mu;
        float rstd = rsqrtf(var + 1e-5f);
        #pragma unroll
        for (int kk = 0; kk < 4; ++kk) {
            int c = tid * 4 + kk;
            float y = (v[kk] - mu) * rstd * gamma[c] + beta[c];
            x[(size_t)row * 1024 + c] = __float2bfloat16(y);
        }
    } else {
        __shared__ __hip_bfloat16 tile[32][33];
        int wid = blockIdx.x - 4096;         // 0..3071
        int zz  = wid >> 10;
        int rem = wid & 1023;
        int bx = rem & 31, by = rem >> 5;
        int tx = tid & 31, ty = tid >> 5;    // (32,8)
        const float* src = (zz == 0) ? Wq : (zz == 1) ? Wk : Wv;
        __hip_bfloat16* dst = Wt + (size_t)zz * 1024 * 1024;
        int x0 = bx * 32, y0 = by * 32;
        #pragma unroll
        for (int kk = 0; kk < 4; ++kk)
            tile[ty + 8 * kk][tx] =
                __float2bfloat16(src[(size_t)(y0 + ty + 8 * kk) * 1024 + x0 + tx]);
        __syncthreads();
        #pragma unroll
        for (int kk = 0; kk < 4; ++kk)
            dst[(size_t)(x0 + ty + 8 * kk) * 1024 + y0 + tx] = tile[tx][ty + 8 * kk];
    }
}

// ---------------------------------------------------------------------------
// Kernel 2: fused QKV GEMM. m97 loop (BK=64, XOR-swizzled LDS) with ROTATED
// pipeline: stage(n+1) issued after barrier-2, before MFMA(n) — the MFMA
// block shadows the staging latency. Coalesced LDS-bounce epilogue;
// t==2 (V) bounce transposed straight into vt.  (round-0 proven version)
// ---------------------------------------------------------------------------
__global__ __launch_bounds__(256) void qkv_gemm(
    const __hip_bfloat16* __restrict__ X,    // [4096,1024] bf16
    const __hip_bfloat16* __restrict__ Wt,   // [3][1024][1024] bf16 N-major
    const float* __restrict__ bq,
    const float* __restrict__ bk,
    const float* __restrict__ bv,
    __hip_bfloat16* __restrict__ qkv,        // [2][4096][1024] bf16 (q,k)
    __hip_bfloat16* __restrict__ vt)         // [64][64][1024] bf16
{
    union SMem {
        struct { __hip_bfloat16 A[128 * 64]; __hip_bfloat16 B[128 * 64]; } s;
        __hip_bfloat16 C[128 * 132];         // epilogue bounce (pad 132)
    };
    __shared__ __align__(16) SMem sm;

    const int id   = blockIdx.x;             // 0..767
    const int xcd  = id & 7;
    const int rest = id >> 3;                // 0..95
    const int j    = rest % 3;
    const int mblk = rest / 3;               // 0..31
    const int m0   = mblk * 128;
    const int n0   = (xcd * 3 + j) * 128;    // 0..2944
    const int t    = n0 >> 10;
    const int nn0  = n0 & 1023;
    const __hip_bfloat16* W = Wt + (size_t)t * 1024 * 1024;

    const int tid  = threadIdx.x;
    const int wave = tid >> 6, lane = tid & 63;
    const int wm = wave & 1, wn = wave >> 1;
    const int lm = lane & 15, quad = lane >> 4;

    const int srow = lane >> 3;                        // 0..7
    const int skc  = ((lane & 7) ^ srow) * 8;          // element offset
    const int rbase = wave * 32;                       // rows this wave stages
    const __hip_bfloat16* gA = X + (size_t)(m0 + rbase + srow) * 1024 + skc;
    const __hip_bfloat16* gB = W + (size_t)(nn0 + rbase + srow) * 1024 + skc;
    __hip_bfloat16* lA = sm.s.A + rbase * 64;
    __hip_bfloat16* lB = sm.s.B + rbase * 64;

    f32x4 acc[4][4];
    #pragma unroll
    for (int i = 0; i < 4; ++i)
        #pragma unroll
        for (int jj = 0; jj < 4; ++jj)
            acc[i][jj] = (f32x4){0.f, 0.f, 0.f, 0.f};

    // prologue: stage tile 0
    #pragma unroll
    for (int n = 0; n < 4; ++n) {
        gld16(gA + (size_t)n * 8 * 1024, lA + n * 8 * 64);
        gld16(gB + (size_t)n * 8 * 1024, lB + n * 8 * 64);
    }

    for (int k0 = 0; k0 < 1024; k0 += 64) {
        __syncthreads();                     // drains stage(k0) (vmcnt in barrier)

        bf16x8 a[2][4], b[2][4];
        #pragma unroll
        for (int ks = 0; ks < 2; ++ks) {
            #pragma unroll
            for (int i = 0; i < 4; ++i) {
                int row = wm * 64 + i * 16 + lm;
                a[ks][i] = *(const bf16x8*)(sm.s.A + (size_t)row * 64
                                            + (((ks * 4 + quad) ^ (lm & 7)) * 8));
            }
            #pragma unroll
            for (int jj = 0; jj < 4; ++jj) {
                int row = wn * 64 + jj * 16 + lm;
                b[ks][jj] = *(const bf16x8*)(sm.s.B + (size_t)row * 64
                                             + (((ks * 4 + quad) ^ (lm & 7)) * 8));
            }
        }
        __syncthreads();                     // all LDS reads done

        if (k0 + 64 < 1024) {                // stage(k0+64) under MFMA shadow
            #pragma unroll
            for (int n = 0; n < 4; ++n) {
                gld16(gA + (size_t)n * 8 * 1024 + k0 + 64, lA + n * 8 * 64);
                gld16(gB + (size_t)n * 8 * 1024 + k0 + 64, lB + n * 8 * 64);
            }
        }

        #pragma unroll
        for (int ks = 0; ks < 2; ++ks)
            #pragma unroll
            for (int i = 0; i < 4; ++i)
                #pragma unroll
                for (int jj = 0; jj < 4; ++jj)
                    acc[i][jj] = __builtin_amdgcn_mfma_f32_16x16x32_bf16(a[ks][i], b[ks][jj], acc[i][jj], 0, 0, 0);
    }

    const float* bias = (t == 0) ? bq : (t == 1) ? bk : bv;
    if (t < 2) {
        #pragma unroll
        for (int jj = 0; jj < 4; ++jj) {
            int col = wn * 64 + jj * 16 + lm;
            float bb = bias[nn0 + col];
            #pragma unroll
            for (int i = 0; i < 4; ++i)
                #pragma unroll
                for (int r = 0; r < 4; ++r) {
                    int row = wm * 64 + i * 16 + quad * 4 + r;
                    sm.C[(size_t)row * 132 + col] = __float2bfloat16(acc[i][jj][r] + bb);
                }
        }
        __syncthreads();
        __hip_bfloat16* out = qkv + (size_t)t * 4096 * 1024;
        #pragma unroll
        for (int c = 0; c < 8; ++c) {
            int g = tid + 256 * c;               // 0..2047 chunks of 16B
            int row = g >> 4;
            int colc = (g & 15) * 8;
            bf16x8 vch = *(const bf16x8*)&sm.C[(size_t)row * 132 + colc];
            *(bf16x8*)(out + (size_t)(m0 + row) * 1024 + nn0 + colc) = vch;
        }
    } else {
        #pragma unroll
        for (int jj = 0; jj < 4; ++jj) {
            int col = wn * 64 + jj * 16 + lm;
            float bb = bias[nn0 + col];
            #pragma unroll
            for (int i = 0; i < 4; ++i)
                #pragma unroll
                for (int r = 0; r < 4; ++r) {
                    int row = wm * 64 + i * 16 + quad * 4 + r;
                    sm.C[(size_t)col * 132 + row] = __float2bfloat16(acc[i][jj][r] + bb);
                }
        }
        __syncthreads();
        const int bbase = (m0 >> 10) * 16 + (nn0 >> 6);
        const int mloc  = m0 & 1023;
        #pragma unroll
        for (int c = 0; c < 8; ++c) {
            int g = tid + 256 * c;               // 0..2047
            int col = g >> 4;                    // 0..127
            int rch = (g & 15) * 8;              // token chunk
            bf16x8 vch = *(const bf16x8*)&sm.C[(size_t)col * 132 + rch];
            int bh = bbase + (col >> 6);
            int d  = col & 63;
            *(bf16x8*)(vt + ((size_t)bh * 64 + d) * 1024 + mloc + rch) = vch;
        }
    }
}

// ---------------------------------------------------------------------------
// Kernel 3: flash attention v10 — 32x32x16 MFMA, in-register P.
// Swapped QK^T (A=K, B=Q^T) -> S^T with col=q=lane&31,
// key=(reg&3)+8*(reg>>2)+4*(lane>>5). P packed to bf16 via v_cvt_pk_bf16_f32,
// redistributed across lane halves via v_permlane32_swap_b32 (T12) to form
// PV's B-operand directly — no ldsPT round-trip. K/V double-buffered (64 KB),
// one barrier per 128-key tile. Max-free softmax (scores bounded), li reduce
// is a single shfl_xor(32).
// ---------------------------------------------------------------------------
__global__ __launch_bounds__(256, 2) void attn_kernel(
    const __hip_bfloat16* __restrict__ q,    // [4096,1024]
    const __hip_bfloat16* __restrict__ k,    // [4096,1024]
    const __hip_bfloat16* __restrict__ vt,   // [64][64][1024]
    float* __restrict__ out)                 // [4096,1024] f32
{
    __shared__ __align__(16) __hip_bfloat16 Kbuf[2][128 * 64];   // 32 KB
    __shared__ __align__(16) __hip_bfloat16 Vbuf[2][2][64 * 64]; // 32 KB
    const int id   = blockIdx.x;             // 0..511
    const int bh   = (id & 7) * 8 + ((id >> 3) & 7);  // XCD-local K/V
    const int qblk = id >> 6;                // 0..7
    const int b = bh >> 4, h = bh & 15;
    const int wave = threadIdx.x >> 6, lane = threadIdx.x & 63;
    const int l31 = lane & 31, hi5 = lane >> 5;
    const int qbase = qblk * 128 + wave * 32;
    const float CEXP = 0.18033688011112042f; // (1/8) * log2(e)

    // Q fragments: B-operand of 32x32x16, col=q=l31, k(d) = 8*hi5 + j per slab
    bf16x8 bq32[4];
    #pragma unroll
    for (int slab = 0; slab < 4; ++slab)
        bq32[slab] = *(const bf16x8*)(q + (size_t)(b * 1024 + qbase + l31) * 1024
                                        + h * 64 + (slab * 2 + hi5) * 8);

    const __hip_bfloat16* kg = k + (size_t)(b * 1024) * 1024 + h * 64;   // [key][d]
    const __hip_bfloat16* vg = vt + (size_t)bh * 64 * 1024;              // [d][key]
    const int srow = lane >> 3;                  // 0..7
    const int skc  = ((lane & 7) ^ srow) * 8;    // swizzled source chunk

    f32x16 OT[2];          // O^T accumulators: [dt], col=q, row=d pattern
    #pragma unroll
    for (int dt = 0; dt < 2; ++dt)
        #pragma unroll
        for (int r = 0; r < 16; ++r)
            OT[dt][r] = 0.f;
    float li = 0.f;

    // stage K [128 keys][64 d] and V [2][64 d][64 keys] for tile `kt` into buf
    auto stageKV = [&](int buf, int kt) {
        #pragma unroll
        for (int n = 0; n < 4; ++n) {
            int r0 = wave * 32 + n * 8;
            gld16(kg + (size_t)(kt + r0 + srow) * 1024 + skc, Kbuf[buf] + r0 * 64);
        }
        int half = wave >> 1;
        #pragma unroll
        for (int n = 0; n < 4; ++n) {
            int d0 = (wave & 1) * 32 + n * 8;
            gld16(vg + (size_t)(d0 + srow) * 1024 + kt + half * 64 + skc,
                  Vbuf[buf][half] + d0 * 64);
        }
    };

    stageKV(0, 0);                           // prologue

    for (int tt = 0; tt < 8; ++tt) {
        __syncthreads();                     // stage(tt) landed; buf^1 readers done
        if (tt + 1 < 8) stageKV((tt + 1) & 1, (tt + 1) * 128);

        const __hip_bfloat16* Kb = Kbuf[tt & 1];

        #pragma unroll
        for (int sr = 0; sr < 2; ++sr) {
            const __hip_bfloat16* Vb = Vbuf[tt & 1][sr];

            // ---- QK^T: S^T[64 keys][32 q], 2 key-tiles x 4 d-slabs ----
            f32x16 ST[2];
            #pragma unroll
            for (int kt = 0; kt < 2; ++kt) {
                #pragma unroll
                for (int r = 0; r < 16; ++r) ST[kt][r] = 0.f;
                #pragma unroll
                for (int slab = 0; slab < 4; ++slab) {
                    bf16x8 ak = *(const bf16x8*)(Kb
                        + (size_t)(sr * 64 + kt * 32 + l31) * 64
                        + (((slab * 2 + hi5) ^ (l31 & 7)) * 8));
                    ST[kt] = __builtin_amdgcn_mfma_f32_32x32x16_bf16(ak, bq32[slab], ST[kt], 0, 0, 0);
                }
            }

            // ---- softmax (max-free) + pack P^T into PV B-operand words ----
            unsigned pw[4][4];               // [ks][word]
            #pragma unroll
            for (int kt = 0; kt < 2; ++kt) {
                float pv[16];
                #pragma unroll
                for (int r = 0; r < 16; ++r) {
                    pv[r] = __builtin_amdgcn_exp2f(ST[kt][r] * CEXP);
                    li += pv[r];
                }
                #pragma unroll
                for (int s = 0; s < 2; ++s) {
                    unsigned P0 = cvtpk(pv[8 * s + 0], pv[8 * s + 1]);
                    unsigned P1 = cvtpk(pv[8 * s + 2], pv[8 * s + 3]);
                    unsigned P2 = cvtpk(pv[8 * s + 4], pv[8 * s + 5]);
                    unsigned P3 = cvtpk(pv[8 * s + 6], pv[8 * s + 7]);
                    asm("v_permlane32_swap_b32 %0, %1" : "+v"(P0), "+v"(P2));
                    asm("v_permlane32_swap_b32 %0, %1" : "+v"(P1), "+v"(P3));
                    int ks = kt * 2 + s;
                    pw[ks][0] = P0; pw[ks][1] = P1; pw[ks][2] = P2; pw[ks][3] = P3;
                }
            }

            // ---- PV: O^T[64 d][32 q] += V^T · P^T ----
            #pragma unroll
            for (int dt = 0; dt < 2; ++dt)
                #pragma unroll
                for (int ks = 0; ks < 4; ++ks) {
                    bf16x8 av = *(const bf16x8*)(Vb
                        + (size_t)(dt * 32 + l31) * 64
                        + (((ks * 2 + hi5) ^ (l31 & 7)) * 8));
                    bf16x8 pf;
                    __builtin_memcpy(&pf, pw[ks], 16);
                    OT[dt] = __builtin_amdgcn_mfma_f32_32x32x16_bf16(av, pf, OT[dt], 0, 0, 0);
                }
        }
    }

    li += __shfl_xor(li, 32);
    float inv = 1.0f / li;
    const int qrow = qbase + l31;

    #pragma unroll
    for (int dt = 0; dt < 2; ++dt)
        #pragma unroll
        for (int g = 0; g < 4; ++g) {
            float4 o4 = {OT[dt][4 * g + 0] * inv, OT[dt][4 * g + 1] * inv,
                         OT[dt][4 * g + 2] * inv, OT[dt][4 * g + 3] * inv};
            *(float4*)(out + (size_t)(b * 1024 + qrow) * 1024
                       + h * 64 + dt * 32 + 8 * g + 4 * hi5) = o4;
        }
}

// ---------------------------------------------------------------------------
extern "C" void kernel_launch(void* const* d_in, const int* in_sizes, int n_in,
                              void* d_out, int out_size, void* d_ws, size_t ws_size,
                              hipStream_t stream)
{
    const float* emb   = (const float*)d_in[0];
    const float* gamma = (const float*)d_in[1];
    const float* beta  = (const float*)d_in[2];
    const float* Wq    = (const float*)d_in[3];
    const float* bq    = (const float*)d_in[4];
    const float* Wk    = (const float*)d_in[5];
    const float* bk    = (const float*)d_in[6];
    const float* Wv    = (const float*)d_in[7];
    const float* bv    = (const float*)d_in[8];
    float* out = (float*)d_out;

    __hip_bfloat16* ws  = (__hip_bfloat16*)d_ws;
    __hip_bfloat16* x   = ws;                            //  4M elems bf16
    __hip_bfloat16* Wt  = x   + (size_t)4096 * 1024;     //  3M elems
    __hip_bfloat16* qkv = Wt  + (size_t)3 * 1024 * 1024; //  8M elems (q,k)
    __hip_bfloat16* vt  = qkv + (size_t)2 * 4096 * 1024; //  4M elems (38MB)

    peln_wt_kernel<<<4096 + 3072, 256, 0, stream>>>(emb, gamma, beta, Wq, Wk, Wv, x, Wt);
    qkv_gemm<<<768, 256, 0, stream>>>(x, Wt, bq, bk, bv, qkv, vt);
    attn_kernel<<<512, 256, 0, stream>>>(qkv, qkv + (size_t)4096 * 1024, vt, out);
}